// Round 13
// baseline (425.137 us; speedup 1.0000x reference)
//
#include <hip/hip_runtime.h>
#include <hip/hip_bf16.h>
#include <cstdint>
#include <cstddef>

// CFnetFilter: w_ij = segment_sum(ssp(ssp(dijk@W1+b1)@W2+b2), seg_j)
//
// R13 = R12 (base-2 softplus diet + hoisted swizzle addrs, 423us) + half-tile
// software pipeline. 128-row tile split into 64-row halves A/B (16KB each,
// LDS total still 32KB -> 3 blocks/CU). Phases pair an MFMA stream on one
// half with a VALU/DS stream on the other, so pipes overlap inside every
// phase instead of alternating pure-MFMA / pure-VALU phases:
//   P0 stage(A) | P1 loadB,GEMM1(A),writeB | P2 GEMM1(B),sp1(A)
//   P3 GEMM2(A),sp1(B) | P4 GEMM2(B),sp2(A) | P5 sp2(B) | P6 reduce.
// T14: B's global loads issue before GEMM1(A), ds-writes after (HBM latency
// hidden under MFMA). acc registers: accA[4]+accB[4] = 32, same as R12.

typedef float  f32x4  __attribute__((ext_vector_type(4)));
typedef __bf16 bf16x8 __attribute__((ext_vector_type(8)));

// may_alias views for LDS type-punning (R5 lesson)
typedef uint32_t u32a    __attribute__((may_alias));
typedef bf16x8   bf16x8a __attribute__((may_alias));
typedef __bf16   bf16a   __attribute__((may_alias));

static constexpr int   N_TRIPLES = 2000000;
static constexpr int   DIM       = 128;
static constexpr int   NSEG      = 100000;
static constexpr int   ROWS      = 128;     // rows per block (2e6 / 128 exact)
static constexpr float LOG2F_    = 0.6931471805599453f;   // ln2
static constexpr float LOG2E_    = 1.4426950408889634f;   // 1/ln2

// base-2 softplus core: u = max(y,0) + log2(1 + 2^-|y|)
__device__ __forceinline__ float sp2_(float y) {
  float t = __builtin_amdgcn_exp2f(-__builtin_fabsf(y));   // v_exp with -abs mods
  return fmaxf(y, 0.0f) + __builtin_amdgcn_logf(1.0f + t); // v_log = log2
}

// WT1 = (W1*log2e)^T bf16 ; WT2 = W2^T bf16  (B-frags contiguous in k)
__global__ void wt_kernel(const float* __restrict__ W1, const float* __restrict__ W2,
                          __bf16* __restrict__ WT) {
  int t = blockIdx.x * 256 + threadIdx.x;   // 0..16383
  int k = t >> 7;
  int n = t & 127;
  WT[n * 128 + k]         = (__bf16)(W1[t] * LOG2E_);
  WT[16384 + n * 128 + k] = (__bf16)W2[t];
}

// b1p[n] = b1[n]*log2e ;  b2p[n] = (b2[n] - ln2*sum_k W2[k][n]) * log2e
__global__ void bias_kernel(const float* __restrict__ b1, const float* __restrict__ W2,
                            const float* __restrict__ b2,
                            float* __restrict__ b1p, float* __restrict__ b2p) {
  int n = threadIdx.x;
  float s = 0.0f;
  #pragma unroll 8
  for (int k = 0; k < 128; ++k) s += W2[k * 128 + n];
  b1p[n] = b1[n] * LOG2E_;
  b2p[n] = (b2[n] - LOG2F_ * s) * LOG2E_;
}

__global__ __launch_bounds__(512, 6) void fused_kernel(
    const float* __restrict__ dijk, const int* __restrict__ seg,
    const __bf16* __restrict__ WT,
    const float* __restrict__ b1v, const float* __restrict__ b2p,
    float* __restrict__ out)
{
  __shared__ __bf16 tile[ROWS * DIM];   // 32 KB; bufA = rows 0-63, bufB = 64-127

  const int tid  = threadIdx.x;         // 0..511
  const int lane = tid & 63;
  const int wave = tid >> 6;            // 0..7 -> col slice [16w, 16w+16)
  const int l15  = lane & 15;
  const int g    = lane >> 4;           // k-group
  const int r0   = blockIdx.x * ROWS;

  char* tA = (char*)tile;
  char* tB = (char*)tile + 16384;

  // ---- staging geometry: thread -> (row 0..63, oct 0..7), 16 f32 each ----
  const int  srow = tid >> 3;
  const int  soct = tid & 7;
  const int  sswz = (srow & 7) << 4;
  char* sdstA = tA + srow * 256;
  char* sdstB = tB + srow * 256;
  const uint32_t so0 = (uint32_t)((soct * 32)      ^ sswz);
  const uint32_t so1 = (uint32_t)((soct * 32 + 16) ^ sswz);
  const float* gsrcA = dijk + (size_t)(r0 + srow) * DIM + soct * 16;
  const float* gsrcB = gsrcA + (size_t)64 * DIM;

  const int colw = wave * 16 + l15;       // this lane's output column
  const float bias1 = b1v[colw];
  const float bias2 = b2p[colw];

  // hoisted GEMM addressing (local rows; row&7 mt-invariant, 16 % 8 == 0)
  const int  swA = (l15 & 7) << 4;
  uint32_t bo[4];
  #pragma unroll
  for (int ks = 0; ks < 4; ++ks) bo[ks] = (uint32_t)((ks * 64 + g * 16) ^ swA);
  uint32_t wbase[4];
  #pragma unroll
  for (int j = 0; j < 4; ++j) {
    int rj = g * 4 + j;
    wbase[j] = (uint32_t)(rj * 256 + ((colw * 2) ^ ((rj & 7) << 4)));
  }

  // ---- P0: stage A ----
  {
    f32x4 v0 = *(const f32x4*)(gsrcA);
    f32x4 v1 = *(const f32x4*)(gsrcA + 4);
    f32x4 v2 = *(const f32x4*)(gsrcA + 8);
    f32x4 v3 = *(const f32x4*)(gsrcA + 12);
    bf16x8 t8a, t8b;
    t8a[0]=(__bf16)v0[0]; t8a[1]=(__bf16)v0[1]; t8a[2]=(__bf16)v0[2]; t8a[3]=(__bf16)v0[3];
    t8a[4]=(__bf16)v1[0]; t8a[5]=(__bf16)v1[1]; t8a[6]=(__bf16)v1[2]; t8a[7]=(__bf16)v1[3];
    t8b[0]=(__bf16)v2[0]; t8b[1]=(__bf16)v2[1]; t8b[2]=(__bf16)v2[2]; t8b[3]=(__bf16)v2[3];
    t8b[4]=(__bf16)v3[0]; t8b[5]=(__bf16)v3[1]; t8b[6]=(__bf16)v3[2]; t8b[7]=(__bf16)v3[3];
    *(bf16x8a*)(sdstA + so0) = t8a;
    *(bf16x8a*)(sdstA + so1) = t8b;
  }
  __syncthreads();   // BAR1: A staged

  // ---- P1: issue B loads ; GEMM1(A) ; write B ----
  f32x4 accA[4];
  {
    f32x4 v0 = *(const f32x4*)(gsrcB);          // in flight across GEMM1(A)
    f32x4 v1 = *(const f32x4*)(gsrcB + 4);
    f32x4 v2 = *(const f32x4*)(gsrcB + 8);
    f32x4 v3 = *(const f32x4*)(gsrcB + 12);

    bf16x8 bf1[4];
    #pragma unroll
    for (int ks = 0; ks < 4; ++ks)
      bf1[ks] = *(const bf16x8*)(WT + colw * 128 + ks * 32 + g * 8);

    #pragma unroll
    for (int mt = 0; mt < 4; ++mt) accA[mt] = (f32x4){0.f, 0.f, 0.f, 0.f};
    #pragma unroll
    for (int mt = 0; mt < 4; ++mt) {
      const char* pm = tA + l15 * 256 + mt * 4096;
      #pragma unroll
      for (int ks = 0; ks < 4; ++ks) {
        bf16x8 a = *(const bf16x8a*)(pm + bo[ks]);
        accA[mt] = __builtin_amdgcn_mfma_f32_16x16x32_bf16(a, bf1[ks], accA[mt], 0, 0, 0);
      }
    }

    bf16x8 t8a, t8b;
    t8a[0]=(__bf16)v0[0]; t8a[1]=(__bf16)v0[1]; t8a[2]=(__bf16)v0[2]; t8a[3]=(__bf16)v0[3];
    t8a[4]=(__bf16)v1[0]; t8a[5]=(__bf16)v1[1]; t8a[6]=(__bf16)v1[2]; t8a[7]=(__bf16)v1[3];
    t8b[0]=(__bf16)v2[0]; t8b[1]=(__bf16)v2[1]; t8b[2]=(__bf16)v2[2]; t8b[3]=(__bf16)v2[3];
    t8b[4]=(__bf16)v3[0]; t8b[5]=(__bf16)v3[1]; t8b[6]=(__bf16)v3[2]; t8b[7]=(__bf16)v3[3];
    *(bf16x8a*)(sdstB + so0) = t8a;
    *(bf16x8a*)(sdstB + so1) = t8b;
  }
  __syncthreads();   // BAR2: A's GEMM1 reads done; B staged

  // ---- P2: GEMM1(B) ; sp1(A) -> tA ----
  f32x4 accB[4];
  {
    bf16x8 bf1[4];
    #pragma unroll
    for (int ks = 0; ks < 4; ++ks)
      bf1[ks] = *(const bf16x8*)(WT + colw * 128 + ks * 32 + g * 8);
    #pragma unroll
    for (int mt = 0; mt < 4; ++mt) accB[mt] = (f32x4){0.f, 0.f, 0.f, 0.f};
    #pragma unroll
    for (int mt = 0; mt < 4; ++mt) {
      const char* pm = tB + l15 * 256 + mt * 4096;
      #pragma unroll
      for (int ks = 0; ks < 4; ++ks) {
        bf16x8 a = *(const bf16x8a*)(pm + bo[ks]);
        accB[mt] = __builtin_amdgcn_mfma_f32_16x16x32_bf16(a, bf1[ks], accB[mt], 0, 0, 0);
      }
    }
    #pragma unroll
    for (int mt = 0; mt < 4; ++mt) {
      #pragma unroll
      for (int j = 0; j < 4; ++j) {
        float u1 = sp2_(accA[mt][j] + bias1);
        *(bf16a*)(tA + wbase[j] + mt * 4096) = (__bf16)u1;
      }
    }
  }
  __syncthreads();   // BAR3: B's GEMM1 reads done; u1(A) in tA

  // ---- P3: GEMM2(A) ; sp1(B) -> tB ----
  f32x4 acc2A[4];
  bf16x8 bf2[4];
  {
    #pragma unroll
    for (int ks = 0; ks < 4; ++ks)
      bf2[ks] = *(const bf16x8*)(WT + 16384 + colw * 128 + ks * 32 + g * 8);
    #pragma unroll
    for (int mt = 0; mt < 4; ++mt) acc2A[mt] = (f32x4){0.f, 0.f, 0.f, 0.f};
    #pragma unroll
    for (int mt = 0; mt < 4; ++mt) {
      const char* pm = tA + l15 * 256 + mt * 4096;
      #pragma unroll
      for (int ks = 0; ks < 4; ++ks) {
        bf16x8 a = *(const bf16x8a*)(pm + bo[ks]);
        acc2A[mt] = __builtin_amdgcn_mfma_f32_16x16x32_bf16(a, bf2[ks], acc2A[mt], 0, 0, 0);
      }
    }
    #pragma unroll
    for (int mt = 0; mt < 4; ++mt) {
      #pragma unroll
      for (int j = 0; j < 4; ++j) {
        float u1 = sp2_(accB[mt][j] + bias1);
        *(bf16a*)(tB + wbase[j] + mt * 4096) = (__bf16)u1;
      }
    }
  }
  __syncthreads();   // BAR4: A's GEMM2 reads done; u1(B) in tB

  // ---- P4: GEMM2(B) ; sp2(A) -> tA ----
  f32x4 acc2B[4];
  {
    #pragma unroll
    for (int mt = 0; mt < 4; ++mt) acc2B[mt] = (f32x4){0.f, 0.f, 0.f, 0.f};
    #pragma unroll
    for (int mt = 0; mt < 4; ++mt) {
      const char* pm = tB + l15 * 256 + mt * 4096;
      #pragma unroll
      for (int ks = 0; ks < 4; ++ks) {
        bf16x8 a = *(const bf16x8a*)(pm + bo[ks]);
        acc2B[mt] = __builtin_amdgcn_mfma_f32_16x16x32_bf16(a, bf2[ks], acc2B[mt], 0, 0, 0);
      }
    }
    #pragma unroll
    for (int mt = 0; mt < 4; ++mt) {
      #pragma unroll
      for (int j = 0; j < 4; ++j) {
        float u2 = sp2_(acc2A[mt][j] + bias2);
        float wv = __builtin_fmaf(u2, LOG2F_, -LOG2F_);
        *(bf16a*)(tA + wbase[j] + mt * 4096) = (__bf16)wv;
      }
    }
  }
  __syncthreads();   // BAR5: B's GEMM2 reads done; w(A) in tA

  // ---- P5: sp2(B) -> tB ----
  #pragma unroll
  for (int mt = 0; mt < 4; ++mt) {
    #pragma unroll
    for (int j = 0; j < 4; ++j) {
      float u2 = sp2_(acc2B[mt][j] + bias2);
      float wv = __builtin_fmaf(u2, LOG2F_, -LOG2F_);
      *(bf16a*)(tB + wbase[j] + mt * 4096) = (__bf16)wv;
    }
  }
  __syncthreads();   // BAR6: w(B) in tB; all wijk visible

  // ---- P6: segmented reduce (16 rows/thread; chunks align with halves) ----
  {
    const int colb = (tid & 63) * 2;
    const int hh   = tid >> 6;            // 0..7; hh<4 -> bufA, else bufB
    char* rb = (hh < 4) ? tA : tB;
    const int rloc = (hh & 3) * 16;       // local start row in its buffer
    const int rbeg = hh * 16;             // block-global start row (for seg)
    const int* sp = seg + r0;
    const char* rp[8];
    #pragma unroll
    for (int k = 0; k < 8; ++k)
      rp[k] = rb + rloc * 256 + ((colb * 2) ^ (k << 4));
    float a0 = 0.0f, a1 = 0.0f;
    int cur = sp[rbeg];
    #pragma unroll
    for (int i = 0; i < 16; ++i) {
      int s = sp[rbeg + i];
      if (s != cur) {
        atomicAdd(out + (size_t)cur * DIM + colb,     a0);
        atomicAdd(out + (size_t)cur * DIM + colb + 1, a1);
        a0 = 0.0f; a1 = 0.0f; cur = s;
      }
      uint32_t w = *(const u32a*)(rp[i & 7] + i * 256);
      a0 += __uint_as_float(w << 16);          // bf16 lo -> f32
      a1 += __uint_as_float(w & 0xffff0000u);  // bf16 hi -> f32
    }
    atomicAdd(out + (size_t)cur * DIM + colb,     a0);
    atomicAdd(out + (size_t)cur * DIM + colb + 1, a1);
  }
}

extern "C" void kernel_launch(void* const* d_in, const int* in_sizes, int n_in,
                              void* d_out, int out_size, void* d_ws, size_t ws_size,
                              hipStream_t stream) {
  const float* dijk = (const float*)d_in[0];
  const int*   seg  = (const int*)d_in[1];
  const float* W1   = (const float*)d_in[2];
  const float* b1   = (const float*)d_in[3];
  const float* W2   = (const float*)d_in[4];
  const float* b2   = (const float*)d_in[5];
  float* out = (float*)d_out;

  float*  b1p = (float*)d_ws;                       // 128 f32
  float*  b2p = (float*)((char*)d_ws + 512);        // 128 f32
  __bf16* WT  = (__bf16*)((char*)d_ws + 1024);      // 2 * 128*128 bf16 = 64 KB

  // empty segments must be exactly 0; memset re-zeroes every replay
  (void)hipMemsetAsync(out, 0, (size_t)NSEG * DIM * sizeof(float), stream);

  wt_kernel<<<64, 256, 0, stream>>>(W1, W2, WT);
  bias_kernel<<<1, 128, 0, stream>>>(b1, W2, b2, b1p, b2p);

  fused_kernel<<<N_TRIPLES / ROWS, 512, 0, stream>>>(dijk, seg, WT, b1p, b2p, out);
}